// Round 7
// baseline (344.239 us; speedup 1.0000x reference)
//
#include <hip/hip_runtime.h>
#include <hip/hip_bf16.h>
#include <stdint.h>

#define S_LEN 4096
#define D_DIM 256
#define NBATCH 4
#define KVBLK 32
#define NSUP 32   // super-steps; group gid handles tiles {4s + gid}

typedef unsigned short u16;
typedef float  f32x4  __attribute__((ext_vector_type(4)));
typedef __bf16 bf16x8 __attribute__((ext_vector_type(8)));
typedef __bf16 bf16x4 __attribute__((ext_vector_type(4)));
typedef short  s16x8  __attribute__((ext_vector_type(8)));
typedef short  s16x4  __attribute__((ext_vector_type(4)));

#define AS1 __attribute__((address_space(1)))
#define AS3 __attribute__((address_space(3)))

__device__ __forceinline__ f32x4 mfma16(bf16x8 a, bf16x8 b, f32x4 c) {
  return __builtin_amdgcn_mfma_f32_16x16x32_bf16(a, b, c, 0, 0, 0);
}

__device__ __forceinline__ s16x4 cvt4(float x, float y, float z, float w) {
  bf16x4 b;
  b[0] = (__bf16)x; b[1] = (__bf16)y; b[2] = (__bf16)z; b[3] = (__bf16)w;
  return __builtin_bit_cast(s16x4, b);
}

__device__ __forceinline__ void gload16(const void* g, void* l) {
  __builtin_amdgcn_global_load_lds((const AS1 unsigned int*)g,
                                   (AS3 unsigned int*)l, 16, 0, 0);
}

__global__ void convert_bf16_kernel(const float* __restrict__ in,
                                    u16* __restrict__ out, int n4) {
  int i = blockIdx.x * blockDim.x + threadIdx.x;
  if (i >= n4) return;
  float4 f = reinterpret_cast<const float4*>(in)[i];
  reinterpret_cast<s16x4*>(out)[i] = cvt4(f.x, f.y, f.z, f.w);
}

// ---------------------------------------------------------------------------
// R7 = R6 geometry (verified correct) with the staging schedule fixed:
//   per super-step: [publish] QK^T  [bar B: K reads done]
//                   issue gloadK(next) + V-reg loads(next)
//                   softmax + PV   (covers the load latency)
//                   [bar C: V reads done, vmcnt drained]
//                   V ds_write(next)  [publish]
// Layouts (identical to R6, correctness-verified):
//   K tile [32 k][256 d] bf16, byte ^= ((k&7)<<4), staged by global_load_lds
//     with inverse-swizzled per-lane global source (linear LDS dest).
//   V tile [256 d][32 k] bf16 transposed, permuted col(k): lane g's 8 keys
//     = one 16B chunk; 64 B/row; byte ^= ((((d>>4)^d)&3)<<4).
// ---------------------------------------------------------------------------

__device__ __forceinline__
void qkt_half(const char* KsB, const bf16x8 (&qf)[2][8], f32x4 (&st)[2][2],
              int g, int h)
{
  const f32x4 fz = {0.f, 0.f, 0.f, 0.f};
  st[0][0] = fz; st[0][1] = fz; st[1][0] = fz; st[1][1] = fz;
  __builtin_amdgcn_s_setprio(1);
  #pragma unroll
  for (int t = 0; t < 2; ++t) {
    const int row = t * 16 + h;
    const int sw  = (row & 7) << 4;
    #pragma unroll
    for (int dc = 0; dc < 8; ++dc) {
      s16x8 kf = *reinterpret_cast<const s16x8*>(KsB + row * 512 + ((dc * 64 + g * 16) ^ sw));
      st[0][t] = mfma16(__builtin_bit_cast(bf16x8, kf), qf[0][dc], st[0][t]);
      st[1][t] = mfma16(__builtin_bit_cast(bf16x8, kf), qf[1][dc], st[1][t]);
    }
  }
  __builtin_amdgcn_s_setprio(0);
}

__device__ __forceinline__
void pv_half(const char* VtB, f32x4 (&st)[2][2], f32x4 (&acc)[2][16],
             float (&m_run)[2], float (&l_run)[2], int g, int h)
{
  bf16x8 pa[2];
  #pragma unroll
  for (int qs = 0; qs < 2; ++qs) {
    float sv[8];
    #pragma unroll
    for (int t = 0; t < 2; ++t) {
      sv[t * 4 + 0] = st[qs][t][0]; sv[t * 4 + 1] = st[qs][t][1];
      sv[t * 4 + 2] = st[qs][t][2]; sv[t * 4 + 3] = st[qs][t][3];
    }
    float tmax = sv[0];
    #pragma unroll
    for (int i = 1; i < 8; ++i) tmax = fmaxf(tmax, sv[i]);
    tmax = fmaxf(tmax, __shfl_xor(tmax, 16));
    tmax = fmaxf(tmax, __shfl_xor(tmax, 32));

    if (!__all(tmax <= m_run[qs] + 8.0f)) {     // T13 defer-max
      const float mnew  = fmaxf(m_run[qs], tmax);
      const float alpha = __expf(m_run[qs] - mnew);
      l_run[qs] *= alpha;
      float af[4];
      #pragma unroll
      for (int r = 0; r < 4; ++r) af[r] = __shfl(alpha, g * 4 + r);
      #pragma unroll
      for (int dt = 0; dt < 16; ++dt) {
        acc[qs][dt][0] *= af[0]; acc[qs][dt][1] *= af[1];
        acc[qs][dt][2] *= af[2]; acc[qs][dt][3] *= af[3];
      }
      m_run[qs] = mnew;
    }

    float psum = 0.f;
    #pragma unroll
    for (int i = 0; i < 8; ++i) { sv[i] = __expf(sv[i] - m_run[qs]); psum += sv[i]; }
    psum += __shfl_xor(psum, 16);
    psum += __shfl_xor(psum, 32);
    l_run[qs] += psum;

    #pragma unroll
    for (int j = 0; j < 8; ++j) pa[qs][j] = (__bf16)sv[j];
  }

  __builtin_amdgcn_s_setprio(1);
  #pragma unroll
  for (int dt = 0; dt < 16; ++dt) {
    const int d = dt * 16 + h;
    s16x8 vf = *reinterpret_cast<const s16x8*>(VtB + d * 64 + ((16 * g) ^ (((dt ^ h) & 3) << 4)));
    acc[0][dt] = mfma16(pa[0], __builtin_bit_cast(bf16x8, vf), acc[0][dt]);
    acc[1][dt] = mfma16(pa[1], __builtin_bit_cast(bf16x8, vf), acc[1][dt]);
  }
  __builtin_amdgcn_s_setprio(0);
}

template<bool USE_WS>
__global__ __launch_bounds__(512, 2)
void attn_fwd_kernel(const float* __restrict__ Qg, const void* __restrict__ Kp,
                     const void* __restrict__ Vp, float* __restrict__ Og)
{
  __shared__ __align__(16) char smem[133120];  // 4 x 32KB tile bufs + 2KB ml

  const int wg   = blockIdx.x;                 // 256 WGs (1 per CU)
  const int swz  = (wg & 7) * 32 + (wg >> 3);  // bijective XCD swizzle
  const int b    = swz >> 6;
  const int qt   = swz & 63;
  const int tid  = threadIdx.x;
  const int wave = tid >> 6;                   // 0..7
  const int lane = tid & 63;
  const int g    = lane >> 4;
  const int h    = lane & 15;
  const int gid  = wave >> 1;                  // K-split group 0..3
  const int wq   = wave & 1;                   // q-half within group
  const int ltid = tid & 127;                  // intra-group thread id

  // V staging roles (per group, 128 threads): keys 4*kb..4*kb+3, d-chunk dcq
  const int kb  = ltid & 7;
  const int dcq = ltid >> 3;
  const int Xw  = 16 * (kb & 3) + 8 * (kb >> 2);

  char* KsB = smem + gid * 32768;
  char* VtB = KsB + 16384;
  float2* mlS = reinterpret_cast<float2*>(smem + 131072);

  const int qbase = qt * 64 + wq * 32;

  // Q fragments (B-operand of swapped QK^T), pre-scaled by 1/sqrt(256)
  bf16x8 qf[2][8];
  #pragma unroll
  for (int qs = 0; qs < 2; ++qs) {
    const float* qrow = Qg + ((size_t)b * S_LEN + qbase + qs * 16 + h) * D_DIM;
    #pragma unroll
    for (int dc = 0; dc < 8; ++dc) {
      float4 f0 = *reinterpret_cast<const float4*>(qrow + dc * 32 + g * 8);
      float4 f1 = *reinterpret_cast<const float4*>(qrow + dc * 32 + g * 8 + 4);
      bf16x8 q;
      q[0] = (__bf16)(f0.x * 0.0625f); q[1] = (__bf16)(f0.y * 0.0625f);
      q[2] = (__bf16)(f0.z * 0.0625f); q[3] = (__bf16)(f0.w * 0.0625f);
      q[4] = (__bf16)(f1.x * 0.0625f); q[5] = (__bf16)(f1.y * 0.0625f);
      q[6] = (__bf16)(f1.z * 0.0625f); q[7] = (__bf16)(f1.w * 0.0625f);
      qf[qs][dc] = q;
    }
  }

  f32x4 acc[2][16];
  const f32x4 fz = {0.f, 0.f, 0.f, 0.f};
  #pragma unroll
  for (int qs = 0; qs < 2; ++qs)
    #pragma unroll
    for (int i = 0; i < 16; ++i) acc[qs][i] = fz;
  float m_run[2] = {-1e30f, -1e30f};
  float l_run[2] = {0.f, 0.f};

  if constexpr (USE_WS) {
    const u16* Kb = (const u16*)Kp + (size_t)b * S_LEN * D_DIM;
    const u16* Vb = (const u16*)Vp + (size_t)b * S_LEN * D_DIM;

    // K gload addressing: LDS byte = wq*8192 + i*1024 + 16*lane maps to
    // k = wq*16 + 2i + (lane>>5), col elems = ((lane&31)*8) ^ ((k&7)<<3).
    const int kb0     = wq * 16 + (lane >> 5);
    const int colbase = (lane & 31) * 8;

    const u16* vsrc = Vb + (size_t)(kb * 4) * D_DIM + dcq * 16;

    s16x8 vlo[4], vhi[4];

    // ---- prologue: stage tile gid ----
    {
      const size_t nb = (size_t)gid * KVBLK * D_DIM;
      const u16* kt_ptr = Kb + nb;
      #pragma unroll
      for (int i = 0; i < 8; ++i) {
        const int k = kb0 + 2 * i;
        gload16(kt_ptr + k * 256 + (colbase ^ ((k & 7) << 3)),
                KsB + wq * 8192 + i * 1024);
      }
      #pragma unroll
      for (int r = 0; r < 4; ++r) {
        const u16* s = vsrc + nb + (size_t)r * D_DIM;
        vlo[r] = *reinterpret_cast<const s16x8*>(s);
        vhi[r] = *reinterpret_cast<const s16x8*>(s + 8);
      }
      #pragma unroll
      for (int j = 0; j < 8; ++j) {
        s16x4 c0, c1;
        c0[0] = vlo[0][j]; c0[1] = vlo[1][j]; c0[2] = vlo[2][j]; c0[3] = vlo[3][j];
        c1[0] = vhi[0][j]; c1[1] = vhi[1][j]; c1[2] = vhi[2][j]; c1[3] = vhi[3][j];
        const int d0 = dcq * 16 + j;
        const int d1 = d0 + 8;
        *reinterpret_cast<s16x4*>(VtB + d0 * 64 + (Xw ^ ((((d0 >> 4) ^ d0) & 3) << 4))) = c0;
        *reinterpret_cast<s16x4*>(VtB + d1 * 64 + (Xw ^ ((((d1 >> 4) ^ d1) & 3) << 4))) = c1;
      }
    }
    __syncthreads();   // publish tile 0 (compiler drains vmcnt + lgkm)

    // ---- main loop: 3-barrier schedule hides K/V load latency under PV ----
    for (int s = 0; s < NSUP - 1; ++s) {
      f32x4 st[2][2];
      qkt_half(KsB, qf, st, g, h);
      __syncthreads();   // bar B: all K-LDS reads done (nothing to drain)

      const size_t nb = (size_t)(4 * (s + 1) + gid) * KVBLK * D_DIM;
      {
        const u16* kt_ptr = Kb + nb;
        #pragma unroll
        for (int i = 0; i < 8; ++i) {
          const int k = kb0 + 2 * i;
          gload16(kt_ptr + k * 256 + (colbase ^ ((k & 7) << 3)),
                  KsB + wq * 8192 + i * 1024);
        }
      }
      #pragma unroll
      for (int r = 0; r < 4; ++r) {
        const u16* sp = vsrc + nb + (size_t)r * D_DIM;
        vlo[r] = *reinterpret_cast<const s16x8*>(sp);
        vhi[r] = *reinterpret_cast<const s16x8*>(sp + 8);
      }

      pv_half(VtB, st, acc, m_run, l_run, g, h);  // covers load latency

      __syncthreads();   // bar C: V-LDS reads done; vmcnt drained here
      #pragma unroll
      for (int j = 0; j < 8; ++j) {
        s16x4 c0, c1;
        c0[0] = vlo[0][j]; c0[1] = vlo[1][j]; c0[2] = vlo[2][j]; c0[3] = vlo[3][j];
        c1[0] = vhi[0][j]; c1[1] = vhi[1][j]; c1[2] = vhi[2][j]; c1[3] = vhi[3][j];
        const int d0 = dcq * 16 + j;
        const int d1 = d0 + 8;
        *reinterpret_cast<s16x4*>(VtB + d0 * 64 + (Xw ^ ((((d0 >> 4) ^ d0) & 3) << 4))) = c0;
        *reinterpret_cast<s16x4*>(VtB + d1 * 64 + (Xw ^ ((((d1 >> 4) ^ d1) & 3) << 4))) = c1;
      }
      __syncthreads();   // publish next tiles
    }
    {
      f32x4 st[2][2];
      qkt_half(KsB, qf, st, g, h);
      pv_half(VtB, st, acc, m_run, l_run, g, h);
    }

  } else {
    // fallback: fp32 inputs, serial in-kernel bf16 staging, same layouts
    const float* Kf = (const float*)Kp + (size_t)b * S_LEN * D_DIM;
    const float* Vf = (const float*)Vp + (size_t)b * S_LEN * D_DIM;
    const int rk = ltid >> 2, ck = ltid & 3;
    for (int s = 0; s < NSUP; ++s) {
      const int tile = 4 * s + gid;
      __syncthreads();
      #pragma unroll
      for (int i = 0; i < 8; ++i) {
        const float* src = Kf + (size_t)(tile * KVBLK + rk) * D_DIM + ck * 64 + i * 8;
        float4 f0 = *reinterpret_cast<const float4*>(src);
        float4 f1 = *reinterpret_cast<const float4*>(src + 4);
        char* dst = KsB + rk * 512 + ((ck * 128 + i * 16) ^ ((rk & 7) << 4));
        *reinterpret_cast<s16x4*>(dst)     = cvt4(f0.x, f0.y, f0.z, f0.w);
        *reinterpret_cast<s16x4*>(dst + 8) = cvt4(f1.x, f1.y, f1.z, f1.w);
      }
      {
        s16x8 lo[4], hi[4];
        #pragma unroll
        for (int r = 0; r < 4; ++r) {
          const float* src = Vf + (size_t)(tile * KVBLK + kb * 4 + r) * D_DIM + dcq * 16;
          float4 f0 = *reinterpret_cast<const float4*>(src);
          float4 f1 = *reinterpret_cast<const float4*>(src + 4);
          float4 f2 = *reinterpret_cast<const float4*>(src + 8);
          float4 f3 = *reinterpret_cast<const float4*>(src + 12);
          lo[r] = __builtin_shufflevector(cvt4(f0.x, f0.y, f0.z, f0.w),
                                          cvt4(f1.x, f1.y, f1.z, f1.w), 0, 1, 2, 3, 4, 5, 6, 7);
          hi[r] = __builtin_shufflevector(cvt4(f2.x, f2.y, f2.z, f2.w),
                                          cvt4(f3.x, f3.y, f3.z, f3.w), 0, 1, 2, 3, 4, 5, 6, 7);
        }
        #pragma unroll
        for (int j = 0; j < 8; ++j) {
          s16x4 c0, c1;
          c0[0] = lo[0][j]; c0[1] = lo[1][j]; c0[2] = lo[2][j]; c0[3] = lo[3][j];
          c1[0] = hi[0][j]; c1[1] = hi[1][j]; c1[2] = hi[2][j]; c1[3] = hi[3][j];
          const int d0 = dcq * 16 + j;
          const int d1 = d0 + 8;
          *reinterpret_cast<s16x4*>(VtB + d0 * 64 + (Xw ^ ((((d0 >> 4) ^ d0) & 3) << 4))) = c0;
          *reinterpret_cast<s16x4*>(VtB + d1 * 64 + (Xw ^ ((((d1 >> 4) ^ d1) & 3) << 4))) = c1;
        }
      }
      __syncthreads();
      f32x4 st[2][2];
      qkt_half(KsB, qf, st, g, h);
      pv_half(VtB, st, acc, m_run, l_run, g, h);
    }
  }

  // ---- 4-way split-K merge: 2 rounds through the dead tile buffers ----
  __syncthreads();
  if (gid >= 2) {
    char* base = smem + ((gid - 2) * 2 + wq) * 32768 + lane * 512;
    #pragma unroll
    for (int qs = 0; qs < 2; ++qs)
      #pragma unroll
      for (int dt = 0; dt < 16; ++dt)
        *reinterpret_cast<f32x4*>(base + (((qs * 16 + dt) * 16) ^ ((lane & 7) << 4))) = acc[qs][dt];
    if (lane < 16) {
      float2 a; a.x = m_run[0]; a.y = l_run[0]; mlS[wave * 32 + lane]      = a;
      float2 c; c.x = m_run[1]; c.y = l_run[1]; mlS[wave * 32 + 16 + lane] = c;
    }
  }
  __syncthreads();
  if (gid < 2) {
    const int pw = (gid + 2) * 2 + wq;
    const char* base = smem + (gid * 2 + wq) * 32768 + lane * 512;
    #pragma unroll
    for (int qs = 0; qs < 2; ++qs) {
      const float2 mlB = mlS[pw * 32 + qs * 16 + h];
      const float mN = fmaxf(m_run[qs], mlB.x);
      const float sA = __expf(m_run[qs] - mN);
      const float sB = __expf(mlB.x - mN);
      l_run[qs] = l_run[qs] * sA + mlB.y * sB;
      m_run[qs] = mN;
      float aA[4], aB[4];
      #pragma unroll
      for (int r = 0; r < 4; ++r) { aA[r] = __shfl(sA, g * 4 + r); aB[r] = __shfl(sB, g * 4 + r); }
      #pragma unroll
      for (int dt = 0; dt < 16; ++dt) {
        f32x4 ab = *reinterpret_cast<const f32x4*>(base + (((qs * 16 + dt) * 16) ^ ((lane & 7) << 4)));
        acc[qs][dt][0] = acc[qs][dt][0] * aA[0] + ab[0] * aB[0];
        acc[qs][dt][1] = acc[qs][dt][1] * aA[1] + ab[1] * aB[1];
        acc[qs][dt][2] = acc[qs][dt][2] * aA[2] + ab[2] * aB[2];
        acc[qs][dt][3] = acc[qs][dt][3] * aA[3] + ab[3] * aB[3];
      }
    }
  }
  __syncthreads();
  if (gid == 1) {
    char* base = smem + wq * 32768 + lane * 512;
    #pragma unroll
    for (int qs = 0; qs < 2; ++qs)
      #pragma unroll
      for (int dt = 0; dt < 16; ++dt)
        *reinterpret_cast<f32x4*>(base + (((qs * 16 + dt) * 16) ^ ((lane & 7) << 4))) = acc[qs][dt];
    if (lane < 16) {
      float2 a; a.x = m_run[0]; a.y = l_run[0]; mlS[wave * 32 + lane]      = a;
      float2 c; c.x = m_run[1]; c.y = l_run[1]; mlS[wave * 32 + 16 + lane] = c;
    }
  }
  __syncthreads();
  if (gid == 0) {
    const int pw = 2 + wq;
    const char* base = smem + wq * 32768 + lane * 512;
    float* orow0 = Og + ((size_t)b * S_LEN + qbase) * D_DIM;
    #pragma unroll
    for (int qs = 0; qs < 2; ++qs) {
      const float2 mlB = mlS[pw * 32 + qs * 16 + h];
      const float mN = fmaxf(m_run[qs], mlB.x);
      const float sA = __expf(m_run[qs] - mN);
      const float sB = __expf(mlB.x - mN);
      const float lN = l_run[qs] * sA + mlB.y * sB;
      float aA[4], aB[4], inv[4];
      #pragma unroll
      for (int r = 0; r < 4; ++r) {
        aA[r]  = __shfl(sA, g * 4 + r);
        aB[r]  = __shfl(sB, g * 4 + r);
        inv[r] = 1.f / __shfl(lN, g * 4 + r);
      }
      #pragma unroll
      for (int dt = 0; dt < 16; ++dt) {
        f32x4 ab = *reinterpret_cast<const f32x4*>(base + (((qs * 16 + dt) * 16) ^ ((lane & 7) << 4)));
        #pragma unroll
        for (int r = 0; r < 4; ++r) {
          orow0[(size_t)(qs * 16 + g * 4 + r) * D_DIM + dt * 16 + h] =
              (acc[qs][dt][r] * aA[r] + ab[r] * aB[r]) * inv[r];
        }
      }
    }
  }
}

extern "C" void kernel_launch(void* const* d_in, const int* in_sizes, int n_in,
                              void* d_out, int out_size, void* d_ws, size_t ws_size,
                              hipStream_t stream)
{
  const float* Q = (const float*)d_in[0];
  const float* K = (const float*)d_in[1];
  const float* V = (const float*)d_in[2];
  float* O = (float*)d_out;

  const size_t nelem = (size_t)NBATCH * S_LEN * D_DIM;   // 4,194,304
  const size_t need  = 2 * nelem * sizeof(u16);          // 16 MiB

  if (ws_size >= need) {
    u16* Kb = (u16*)d_ws;
    u16* Vb = Kb + nelem;
    int n4 = (int)(nelem / 4);
    convert_bf16_kernel<<<n4 / 256, 256, 0, stream>>>(K, Kb, n4);
    convert_bf16_kernel<<<n4 / 256, 256, 0, stream>>>(V, Vb, n4);
    attn_fwd_kernel<true><<<256, 512, 0, stream>>>(Q, (const void*)Kb, (const void*)Vb, O);
  } else {
    attn_fwd_kernel<false><<<256, 512, 0, stream>>>(Q, (const void*)K, (const void*)V, O);
  }
}

// Round 9
// 134.027 us; speedup vs baseline: 2.5684x; 2.5684x over previous
//
#include <hip/hip_runtime.h>
#include <hip/hip_bf16.h>
#include <stdint.h>

#define S_LEN 4096
#define D_DIM 256
#define NBATCH 4
#define NKT 64    // 4096 / 64 keys per tile
#define NSUP 32   // super-steps: A computes 2s, B computes 2s+1

typedef unsigned short u16;
typedef float  f32x4  __attribute__((ext_vector_type(4)));
typedef __bf16 bf16x8 __attribute__((ext_vector_type(8)));
typedef __bf16 bf16x4 __attribute__((ext_vector_type(4)));
typedef short  s16x8  __attribute__((ext_vector_type(8)));
typedef short  s16x4  __attribute__((ext_vector_type(4)));

__device__ __forceinline__ f32x4 mfma16(bf16x8 a, bf16x8 b, f32x4 c) {
  return __builtin_amdgcn_mfma_f32_16x16x32_bf16(a, b, c, 0, 0, 0);
}

__device__ __forceinline__ s16x4 cvt4(float x, float y, float z, float w) {
  bf16x4 b;
  b[0] = (__bf16)x; b[1] = (__bf16)y; b[2] = (__bf16)z; b[3] = (__bf16)w;
  return __builtin_bit_cast(s16x4, b);
}

__global__ void convert_bf16_kernel(const float* __restrict__ in,
                                    u16* __restrict__ out, int n4) {
  int i = blockIdx.x * blockDim.x + threadIdx.x;
  if (i >= n4) return;
  float4 f = reinterpret_cast<const float4*>(in)[i];
  reinterpret_cast<s16x4*>(out)[i] = cvt4(f.x, f.y, f.z, f.w);
}

// ---------------------------------------------------------------------------
// R9 = R8 with the Xw scope fix. R8 = R5 (152.8us, verified) with
// producer-consumer phase alternation. Geometry/layouts byte-identical to R5:
//   2 split-K groups x 4 waves; group gid owns buffer gid and tiles {2s+gid}.
//   K tile [64 k][256 d] bf16, byte ^= ((k&7)<<4).
//   V tile [256 d][64 k] bf16 transposed, permuted cols
//          col(k)=16*((k>>2)&3)+4*(k>>4)+(k&3), byte ^= ((d&7)<<4).
// Per half-step, one group computes its staged tile while the OTHER group
// stages its own next tile (global->reg->LDS). 1 barrier per half-step.
// Staging latency hides under the other group's compute (wave-level overlap).
// ---------------------------------------------------------------------------

__device__ __forceinline__
void compute_tile(const char* KsB, const char* vpA, const char* vpB,
                  const bf16x8 (&qf)[8], f32x4 (&acc)[16],
                  float& m_run, float& l_run, int g, int h)
{
  const f32x4 fz = {0.f, 0.f, 0.f, 0.f};

  f32x4 st[4];
  __builtin_amdgcn_s_setprio(1);
  #pragma unroll
  for (int t = 0; t < 4; ++t) {
    f32x4 a = fz;
    const int row = t * 16 + h;
    const int sw  = (row & 7) << 4;
    #pragma unroll
    for (int dc = 0; dc < 8; ++dc) {
      s16x8 kfrag = *reinterpret_cast<const s16x8*>(KsB + row * 512 + ((dc * 64 + g * 16) ^ sw));
      a = mfma16(__builtin_bit_cast(bf16x8, kfrag), qf[dc], a);
    }
    st[t] = a;
  }
  __builtin_amdgcn_s_setprio(0);

  float sv[16];
  #pragma unroll
  for (int t = 0; t < 4; ++t) {
    sv[t * 4 + 0] = st[t][0]; sv[t * 4 + 1] = st[t][1];
    sv[t * 4 + 2] = st[t][2]; sv[t * 4 + 3] = st[t][3];
  }
  float tmax = sv[0];
  #pragma unroll
  for (int i = 1; i < 16; ++i) tmax = fmaxf(tmax, sv[i]);
  tmax = fmaxf(tmax, __shfl_xor(tmax, 16));
  tmax = fmaxf(tmax, __shfl_xor(tmax, 32));

  if (!__all(tmax <= m_run + 8.0f)) {     // T13 defer-max
    const float mnew  = fmaxf(m_run, tmax);
    const float alpha = __expf(m_run - mnew);
    l_run *= alpha;
    const float af0 = __shfl(alpha, g * 4 + 0);
    const float af1 = __shfl(alpha, g * 4 + 1);
    const float af2 = __shfl(alpha, g * 4 + 2);
    const float af3 = __shfl(alpha, g * 4 + 3);
    #pragma unroll
    for (int dt = 0; dt < 16; ++dt) {
      acc[dt][0] *= af0; acc[dt][1] *= af1; acc[dt][2] *= af2; acc[dt][3] *= af3;
    }
    m_run = mnew;
  }

  float psum = 0.f;
  #pragma unroll
  for (int i = 0; i < 16; ++i) { sv[i] = __expf(sv[i] - m_run); psum += sv[i]; }
  psum += __shfl_xor(psum, 16);
  psum += __shfl_xor(psum, 32);
  l_run += psum;

  bf16x8 pa0, pa1;
  #pragma unroll
  for (int j = 0; j < 8; ++j) { pa0[j] = (__bf16)sv[j]; pa1[j] = (__bf16)sv[8 + j]; }

  __builtin_amdgcn_s_setprio(1);
  #pragma unroll
  for (int dt = 0; dt < 16; ++dt) {
    s16x8 v0 = *reinterpret_cast<const s16x8*>(vpA + dt * 2048);
    s16x8 v1 = *reinterpret_cast<const s16x8*>(vpB + dt * 2048);
    acc[dt] = mfma16(pa0, __builtin_bit_cast(bf16x8, v0), acc[dt]);
    acc[dt] = mfma16(pa1, __builtin_bit_cast(bf16x8, v1), acc[dt]);
  }
  __builtin_amdgcn_s_setprio(0);
}

// stage tile `T` (global bf16 -> regs -> LDS), R5's staging code verbatim
__device__ __forceinline__
void stage_tile(int T, const u16* ksrc, char* kdst,
                const u16* vsrc, char* VtB, int Xw, int dcq)
{
  const size_t nb = (size_t)T * 64 * D_DIM;
  s16x8 kreg[8], vlo[4], vhi[4];
  #pragma unroll
  for (int i = 0; i < 8; ++i)
    kreg[i] = *reinterpret_cast<const s16x8*>(ksrc + nb + (size_t)i * 8 * D_DIM);
  #pragma unroll
  for (int r = 0; r < 4; ++r) {
    const u16* s = vsrc + nb + (size_t)r * D_DIM;
    vlo[r] = *reinterpret_cast<const s16x8*>(s);
    vhi[r] = *reinterpret_cast<const s16x8*>(s + 8);
  }
  #pragma unroll
  for (int i = 0; i < 8; ++i)
    *reinterpret_cast<s16x8*>(kdst + i * 4096) = kreg[i];
  #pragma unroll
  for (int j = 0; j < 8; ++j) {
    s16x4 c0, c1;
    c0[0] = vlo[0][j]; c0[1] = vlo[1][j]; c0[2] = vlo[2][j]; c0[3] = vlo[3][j];
    c1[0] = vhi[0][j]; c1[1] = vhi[1][j]; c1[2] = vhi[2][j]; c1[3] = vhi[3][j];
    const int d0 = dcq * 16 + j;
    const int d1 = d0 + 8;
    *reinterpret_cast<s16x4*>(VtB + d0 * 128 + (Xw ^ ((d0 & 7) << 4))) = c0;
    *reinterpret_cast<s16x4*>(VtB + d1 * 128 + (Xw ^ ((d1 & 7) << 4))) = c1;
  }
}

template<bool USE_WS>
__global__ __launch_bounds__(512, 1)
void attn_fwd_kernel(const float* __restrict__ Qg, const void* __restrict__ Kp,
                     const void* __restrict__ Vp, float* __restrict__ Og)
{
  __shared__ __align__(16) char smem[131072];   // 2 x (32KB Ks + 32KB Vt)

  const int wg   = blockIdx.x;                  // 256 WGs (1 per CU)
  const int swz  = (wg & 7) * 32 + (wg >> 3);   // bijective XCD swizzle
  const int b    = swz >> 6;
  const int qt   = swz & 63;
  const int tid  = threadIdx.x;
  const int wave = tid >> 6;                    // 0..7
  const int lane = tid & 63;
  const int g    = lane >> 4;
  const int h    = lane & 15;
  const int gid  = tid >> 8;                    // 0 = group A, 1 = group B
  const int ltid = tid & 255;                   // intra-group thread id
  const int wq   = wave & 3;                    // q-slot within group

  const int kb  = ltid & 15;
  const int dcq = ltid >> 4;
  const int Xw  = 32 * (kb & 3) + 8 * (kb >> 2);   // permuted col chunk base

  char* KsB = smem + gid * 65536;
  char* VtB = KsB + 32768;

  const int qbase = qt * 64 + wq * 16;

  // Q fragments (B-operand of swapped QK^T), pre-scaled by 1/sqrt(256)
  bf16x8 qf[8];
  {
    const float* qrow = Qg + ((size_t)b * S_LEN + qbase + h) * D_DIM;
    #pragma unroll
    for (int dc = 0; dc < 8; ++dc) {
      float4 f0 = *reinterpret_cast<const float4*>(qrow + dc * 32 + g * 8);
      float4 f1 = *reinterpret_cast<const float4*>(qrow + dc * 32 + g * 8 + 4);
      bf16x8 q;
      q[0] = (__bf16)(f0.x * 0.0625f); q[1] = (__bf16)(f0.y * 0.0625f);
      q[2] = (__bf16)(f0.z * 0.0625f); q[3] = (__bf16)(f0.w * 0.0625f);
      q[4] = (__bf16)(f1.x * 0.0625f); q[5] = (__bf16)(f1.y * 0.0625f);
      q[6] = (__bf16)(f1.z * 0.0625f); q[7] = (__bf16)(f1.w * 0.0625f);
      qf[dc] = q;
    }
  }

  f32x4 acc[16];
  const f32x4 fz = {0.f, 0.f, 0.f, 0.f};
  #pragma unroll
  for (int i = 0; i < 16; ++i) acc[i] = fz;
  float m_run = -1e30f;
  float l_run = 0.f;

  const char* vpA = VtB + h * 128 + ((32 * g)      ^ ((h & 7) << 4));
  const char* vpB = VtB + h * 128 + ((32 * g + 16) ^ ((h & 7) << 4));

  if constexpr (USE_WS) {
    const u16* Kb = (const u16*)Kp + (size_t)b * S_LEN * D_DIM;
    const u16* Vb = (const u16*)Vp + (size_t)b * S_LEN * D_DIM;

    const u16* ksrc = Kb + (size_t)(ltid >> 5) * D_DIM + (ltid & 31) * 8;
    char*      kdst = KsB + (ltid >> 5) * 512 + (((ltid & 31) * 16) ^ ((ltid >> 5) << 4));
    const u16* vsrc = Vb + (size_t)(kb * 4) * D_DIM + dcq * 16;

    // ---- prologue: group A stages tile 0 ----
    if (gid == 0) stage_tile(0, ksrc, kdst, vsrc, VtB, Xw, dcq);
    __syncthreads();

    // ---- alternating main loop: 1 barrier per half-step ----
    for (int s = 0; s < NSUP; ++s) {
      // half-step 2s: A computes tile 2s, B stages tile 2s+1
      if (gid == 0) compute_tile(KsB, vpA, vpB, qf, acc, m_run, l_run, g, h);
      else          stage_tile(2 * s + 1, ksrc, kdst, vsrc, VtB, Xw, dcq);
      __syncthreads();
      // half-step 2s+1: B computes tile 2s+1, A stages tile 2s+2
      if (gid == 0) { if (s < NSUP - 1) stage_tile(2 * s + 2, ksrc, kdst, vsrc, VtB, Xw, dcq); }
      else          compute_tile(KsB, vpA, vpB, qf, acc, m_run, l_run, g, h);
      __syncthreads();
    }

  } else {
    // fallback (fp32 inputs, serial staging) — used only if d_ws is too small
    const float* Kf = (const float*)Kp + (size_t)b * S_LEN * D_DIM;
    const float* Vf = (const float*)Vp + (size_t)b * S_LEN * D_DIM;
    for (int s = 0; s < NSUP; ++s) {
      const int kt = 2 * s + gid;
      __syncthreads();
      #pragma unroll
      for (int i = 0; i < 16; ++i) {
        int flat = i * 256 + ltid;
        int kk = flat >> 6;
        int d  = (flat & 63) * 4;
        float4 fk = *reinterpret_cast<const float4*>(Kf + (size_t)(kt * 64 + kk) * D_DIM + d);
        *reinterpret_cast<s16x4*>(KsB + kk * 512 + ((d * 2) ^ ((kk & 7) << 4))) = cvt4(fk.x, fk.y, fk.z, fk.w);
      }
      {
        s16x8 lo[4], hi[4];
        #pragma unroll
        for (int r = 0; r < 4; ++r) {
          const float* src = Vf + (size_t)(kt * 64 + kb * 4 + r) * D_DIM + dcq * 16;
          float4 f0 = *reinterpret_cast<const float4*>(src);
          float4 f1 = *reinterpret_cast<const float4*>(src + 4);
          float4 f2 = *reinterpret_cast<const float4*>(src + 8);
          float4 f3 = *reinterpret_cast<const float4*>(src + 12);
          lo[r] = __builtin_shufflevector(cvt4(f0.x, f0.y, f0.z, f0.w),
                                          cvt4(f1.x, f1.y, f1.z, f1.w), 0, 1, 2, 3, 4, 5, 6, 7);
          hi[r] = __builtin_shufflevector(cvt4(f2.x, f2.y, f2.z, f2.w),
                                          cvt4(f3.x, f3.y, f3.z, f3.w), 0, 1, 2, 3, 4, 5, 6, 7);
        }
        #pragma unroll
        for (int j = 0; j < 8; ++j) {
          s16x4 c0, c1;
          c0[0] = lo[0][j]; c0[1] = lo[1][j]; c0[2] = lo[2][j]; c0[3] = lo[3][j];
          c1[0] = hi[0][j]; c1[1] = hi[1][j]; c1[2] = hi[2][j]; c1[3] = hi[3][j];
          const int d0 = dcq * 16 + j;
          const int d1 = d0 + 8;
          *reinterpret_cast<s16x4*>(VtB + d0 * 128 + (Xw ^ ((d0 & 7) << 4))) = c0;
          *reinterpret_cast<s16x4*>(VtB + d1 * 128 + (Xw ^ ((d1 & 7) << 4))) = c1;
        }
      }
      __syncthreads();
      compute_tile(KsB, vpA, vpB, qf, acc, m_run, l_run, g, h);
    }
  }

  // ---- merge group B's state into group A, then epilogue (R5 verbatim) ----
  __syncthreads();   // all compute done; tile buffers are now dead
  float2* mlM = reinterpret_cast<float2*>(smem + 65536);
  if (gid == 1) {
    const int bw = wave - 4;
    char* base = smem + bw * 16384 + lane * 256;
    #pragma unroll
    for (int dt = 0; dt < 16; ++dt) {
      float4 v; v.x = acc[dt][0]; v.y = acc[dt][1]; v.z = acc[dt][2]; v.w = acc[dt][3];
      *reinterpret_cast<float4*>(base + (dt * 16 ^ ((lane & 7) << 4))) = v;
    }
    if (g == 0) { float2 ml; ml.x = m_run; ml.y = l_run; mlM[bw * 16 + h] = ml; }
  }
  __syncthreads();
  if (gid == 0) {
    const float2 ml = mlM[wave * 16 + h];
    const float mB = ml.x, lB = ml.y;
    const float m  = fmaxf(m_run, mB);
    const float sA = __expf(m_run - m);
    const float sB = __expf(mB - m);
    const float l  = l_run * sA + lB * sB;
    float aA[4], aB[4], inv[4];
    #pragma unroll
    for (int r = 0; r < 4; ++r) {
      aA[r]  = __shfl(sA, g * 4 + r);
      aB[r]  = __shfl(sB, g * 4 + r);
      inv[r] = 1.f / __shfl(l, g * 4 + r);
    }
    const char* base = smem + wave * 16384 + lane * 256;
    float* orow0 = Og + ((size_t)b * S_LEN + qbase) * D_DIM;
    #pragma unroll
    for (int dt = 0; dt < 16; ++dt) {
      float4 ab = *reinterpret_cast<const float4*>(base + (dt * 16 ^ ((lane & 7) << 4)));
      orow0[(size_t)(g * 4 + 0) * D_DIM + h + dt * 16] = (acc[dt][0] * aA[0] + ab.x * aB[0]) * inv[0];
      orow0[(size_t)(g * 4 + 1) * D_DIM + h + dt * 16] = (acc[dt][1] * aA[1] + ab.y * aB[1]) * inv[1];
      orow0[(size_t)(g * 4 + 2) * D_DIM + h + dt * 16] = (acc[dt][2] * aA[2] + ab.z * aB[2]) * inv[2];
      orow0[(size_t)(g * 4 + 3) * D_DIM + h + dt * 16] = (acc[dt][3] * aA[3] + ab.w * aB[3]) * inv[3];
    }
  }
}

extern "C" void kernel_launch(void* const* d_in, const int* in_sizes, int n_in,
                              void* d_out, int out_size, void* d_ws, size_t ws_size,
                              hipStream_t stream)
{
  const float* Q = (const float*)d_in[0];
  const float* K = (const float*)d_in[1];
  const float* V = (const float*)d_in[2];
  float* O = (float*)d_out;

  const size_t nelem = (size_t)NBATCH * S_LEN * D_DIM;   // 4,194,304
  const size_t need  = 2 * nelem * sizeof(u16);          // 16 MiB

  if (ws_size >= need) {
    u16* Kb = (u16*)d_ws;
    u16* Vb = Kb + nelem;
    int n4 = (int)(nelem / 4);
    convert_bf16_kernel<<<n4 / 256, 256, 0, stream>>>(K, Kb, n4);
    convert_bf16_kernel<<<n4 / 256, 256, 0, stream>>>(V, Vb, n4);
    attn_fwd_kernel<true><<<256, 512, 0, stream>>>(Q, (const void*)Kb, (const void*)Vb, O);
  } else {
    attn_fwd_kernel<false><<<256, 512, 0, stream>>>(Q, (const void*)K, (const void*)V, O);
  }
}

// Round 10
// 126.091 us; speedup vs baseline: 2.7301x; 1.0629x over previous
//
#include <hip/hip_runtime.h>
#include <hip/hip_bf16.h>
#include <stdint.h>

#define S_LEN 4096
#define D_DIM 256
#define NBATCH 4
#define NSUP 32   // super-steps: group A computes tiles 2s, group B tiles 2s+1

typedef unsigned short u16;
typedef float  f32x4  __attribute__((ext_vector_type(4)));
typedef __bf16 bf16x8 __attribute__((ext_vector_type(8)));
typedef __bf16 bf16x4 __attribute__((ext_vector_type(4)));
typedef short  s16x8  __attribute__((ext_vector_type(8)));
typedef short  s16x4  __attribute__((ext_vector_type(4)));

#define AS1 __attribute__((address_space(1)))
#define AS3 __attribute__((address_space(3)))

__device__ __forceinline__ f32x4 mfma16(bf16x8 a, bf16x8 b, f32x4 c) {
  return __builtin_amdgcn_mfma_f32_16x16x32_bf16(a, b, c, 0, 0, 0);
}

__device__ __forceinline__ s16x4 cvt4(float x, float y, float z, float w) {
  bf16x4 b;
  b[0] = (__bf16)x; b[1] = (__bf16)y; b[2] = (__bf16)z; b[3] = (__bf16)w;
  return __builtin_bit_cast(s16x4, b);
}

__device__ __forceinline__ void gload16(const void* g, void* l) {
  __builtin_amdgcn_global_load_lds((const AS1 unsigned int*)g,
                                   (AS3 unsigned int*)l, 16, 0, 0);
}

// ---------------------------------------------------------------------------
// R10 = R9 (134us, verified) with LDS-image pre-pass:
//  d_ws holds, per (batch,tile), the EXACT 32KB LDS byte image of the K tile
//  and of the V^T tile (swizzles/permutation baked in).  Staging in the main
//  kernel is then 16x global_load_lds (linear LDS dest, per-lane source) —
//  zero VALU, zero staging registers.  The per-tile transpose work is done
//  ONCE per tile (pre-pass) instead of once per (tile x q-tile WG) = 64x.
// Layout formulas (identical to R9's verified staging):
//  K image: row k (64), chunk p (32x16B): content = K[k][8*(p^(k&7)) .. +8]
//  V image: row d (256), byte position (2*col(k)) ^ ((d&7)<<4) holds V[k][d],
//           col(k) = 16*((k>>2)&3) + 4*(k>>4) + (k&3)
//  inverse: k = (col&3) + 4*(col>>4) + 16*((col>>2)&3)
// ---------------------------------------------------------------------------

__global__ void build_kimg(const float* __restrict__ K, u16* __restrict__ img) {
  const int wg  = blockIdx.x;              // (b*64 + T), 256 WGs
  const int tid = threadIdx.x;
  const float* src = K + (size_t)wg * 64 * D_DIM;
  u16*         dst = img + (size_t)wg * 16384;
  #pragma unroll
  for (int i = 0; i < 8; ++i) {
    const int idx = i * 256 + tid;         // 2048 chunks of 16B
    const int k = idx >> 5, p = idx & 31;
    const int q = p ^ (k & 7);
    const float* s = src + k * 256 + q * 8;
    float4 f0 = *reinterpret_cast<const float4*>(s);
    float4 f1 = *reinterpret_cast<const float4*>(s + 4);
    s16x8 v = __builtin_shufflevector(cvt4(f0.x, f0.y, f0.z, f0.w),
                                      cvt4(f1.x, f1.y, f1.z, f1.w),
                                      0, 1, 2, 3, 4, 5, 6, 7);
    *reinterpret_cast<s16x8*>(dst + k * 256 + p * 8) = v;
  }
}

__global__ void build_vimg(const float* __restrict__ V, u16* __restrict__ img) {
  __shared__ u16 lds[64 * 264];            // V tile bf16, row stride 264 u16
  const int wg  = blockIdx.x;
  const int tid = threadIdx.x;
  const float* src = V + (size_t)wg * 64 * D_DIM;
  u16*         dst = img + (size_t)wg * 16384;
  #pragma unroll
  for (int i = 0; i < 8; ++i) {
    const int idx = i * 256 + tid;
    const int k = idx >> 5, q = idx & 31;  // q: 8-elem d chunk
    const float* s = src + k * 256 + q * 8;
    float4 f0 = *reinterpret_cast<const float4*>(s);
    float4 f1 = *reinterpret_cast<const float4*>(s + 4);
    s16x8 v = __builtin_shufflevector(cvt4(f0.x, f0.y, f0.z, f0.w),
                                      cvt4(f1.x, f1.y, f1.z, f1.w),
                                      0, 1, 2, 3, 4, 5, 6, 7);
    *reinterpret_cast<s16x8*>(&lds[k * 264 + q * 8]) = v;
  }
  __syncthreads();
  #pragma unroll
  for (int i = 0; i < 8; ++i) {
    const int idx = i * 256 + tid;         // 2048 output chunks of 16B
    const int d = idx >> 3, c = idx & 7;
    const int cp = c ^ (d & 7);
    s16x8 o;
    #pragma unroll
    for (int j = 0; j < 8; ++j) {
      const int col = 8 * cp + j;
      const int k = (col & 3) + 4 * (col >> 4) + 16 * ((col >> 2) & 3);
      o[j] = (short)lds[k * 264 + d];
    }
    *reinterpret_cast<s16x8*>(dst + d * 64 + c * 8) = o;
  }
}

// ---- compute one staged tile from LDS (R9 verbatim) ----
__device__ __forceinline__
void compute_tile(const char* KsB, const char* vpA, const char* vpB,
                  const bf16x8 (&qf)[8], f32x4 (&acc)[16],
                  float& m_run, float& l_run, int g, int h)
{
  const f32x4 fz = {0.f, 0.f, 0.f, 0.f};

  f32x4 st[4];
  __builtin_amdgcn_s_setprio(1);
  #pragma unroll
  for (int t = 0; t < 4; ++t) {
    f32x4 a = fz;
    const int row = t * 16 + h;
    const int sw  = (row & 7) << 4;
    #pragma unroll
    for (int dc = 0; dc < 8; ++dc) {
      s16x8 kfrag = *reinterpret_cast<const s16x8*>(KsB + row * 512 + ((dc * 64 + g * 16) ^ sw));
      a = mfma16(__builtin_bit_cast(bf16x8, kfrag), qf[dc], a);
    }
    st[t] = a;
  }
  __builtin_amdgcn_s_setprio(0);

  float sv[16];
  #pragma unroll
  for (int t = 0; t < 4; ++t) {
    sv[t * 4 + 0] = st[t][0]; sv[t * 4 + 1] = st[t][1];
    sv[t * 4 + 2] = st[t][2]; sv[t * 4 + 3] = st[t][3];
  }
  float tmax = sv[0];
  #pragma unroll
  for (int i = 1; i < 16; ++i) tmax = fmaxf(tmax, sv[i]);
  tmax = fmaxf(tmax, __shfl_xor(tmax, 16));
  tmax = fmaxf(tmax, __shfl_xor(tmax, 32));

  if (!__all(tmax <= m_run + 8.0f)) {     // T13 defer-max
    const float mnew  = fmaxf(m_run, tmax);
    const float alpha = __expf(m_run - mnew);
    l_run *= alpha;
    const float af0 = __shfl(alpha, g * 4 + 0);
    const float af1 = __shfl(alpha, g * 4 + 1);
    const float af2 = __shfl(alpha, g * 4 + 2);
    const float af3 = __shfl(alpha, g * 4 + 3);
    #pragma unroll
    for (int dt = 0; dt < 16; ++dt) {
      acc[dt][0] *= af0; acc[dt][1] *= af1; acc[dt][2] *= af2; acc[dt][3] *= af3;
    }
    m_run = mnew;
  }

  float psum = 0.f;
  #pragma unroll
  for (int i = 0; i < 16; ++i) { sv[i] = __expf(sv[i] - m_run); psum += sv[i]; }
  psum += __shfl_xor(psum, 16);
  psum += __shfl_xor(psum, 32);
  l_run += psum;

  bf16x8 pa0, pa1;
  #pragma unroll
  for (int j = 0; j < 8; ++j) { pa0[j] = (__bf16)sv[j]; pa1[j] = (__bf16)sv[8 + j]; }

  __builtin_amdgcn_s_setprio(1);
  #pragma unroll
  for (int dt = 0; dt < 16; ++dt) {
    s16x8 v0 = *reinterpret_cast<const s16x8*>(vpA + dt * 2048);
    s16x8 v1 = *reinterpret_cast<const s16x8*>(vpB + dt * 2048);
    acc[dt] = mfma16(pa0, __builtin_bit_cast(bf16x8, v0), acc[dt]);
    acc[dt] = mfma16(pa1, __builtin_bit_cast(bf16x8, v1), acc[dt]);
  }
  __builtin_amdgcn_s_setprio(0);
}

// ---- stage tile T: pure DMA copy of the 2x32KB images into this group's bufs
__device__ __forceinline__
void stage_img(const u16* KimgB, const u16* VimgB, int T,
               char* KsB, char* VtB, int w, int lane)
{
  const char* ks = (const char*)(KimgB + (size_t)T * 16384) + lane * 16;
  const char* vs = (const char*)(VimgB + (size_t)T * 16384) + lane * 16;
  #pragma unroll
  for (int i = 0; i < 8; ++i) {
    const int off = (i * 4 + w) * 1024;
    gload16(ks + off, KsB + off);
    gload16(vs + off, VtB + off);
  }
}

template<bool USE_WS>
__global__ __launch_bounds__(512, 1)
void attn_fwd_kernel(const float* __restrict__ Qg, const void* __restrict__ Kp,
                     const void* __restrict__ Vp, float* __restrict__ Og)
{
  __shared__ __align__(16) char smem[131072];   // 2 x (32KB Ks + 32KB Vt)

  const int wg   = blockIdx.x;                  // 256 WGs (1 per CU)
  const int swz  = (wg & 7) * 32 + (wg >> 3);   // bijective XCD swizzle
  const int b    = swz >> 6;
  const int qt   = swz & 63;
  const int tid  = threadIdx.x;
  const int wave = tid >> 6;                    // 0..7
  const int lane = tid & 63;
  const int g    = lane >> 4;
  const int h    = lane & 15;
  const int gid  = tid >> 8;                    // 0 = group A, 1 = group B
  const int ltid = tid & 255;                   // intra-group thread id
  const int wq   = wave & 3;                    // q-slot within group
  const int w    = wave & 3;                    // wave index within group

  const int kb  = ltid & 15;                    // (fallback staging roles)
  const int dcq = ltid >> 4;
  const int Xw  = 32 * (kb & 3) + 8 * (kb >> 2);

  char* KsB = smem + gid * 65536;
  char* VtB = KsB + 32768;

  const int qbase = qt * 64 + wq * 16;

  // Q fragments (B-operand of swapped QK^T), pre-scaled by 1/sqrt(256)
  bf16x8 qf[8];
  {
    const float* qrow = Qg + ((size_t)b * S_LEN + qbase + h) * D_DIM;
    #pragma unroll
    for (int dc = 0; dc < 8; ++dc) {
      float4 f0 = *reinterpret_cast<const float4*>(qrow + dc * 32 + g * 8);
      float4 f1 = *reinterpret_cast<const float4*>(qrow + dc * 32 + g * 8 + 4);
      bf16x8 q;
      q[0] = (__bf16)(f0.x * 0.0625f); q[1] = (__bf16)(f0.y * 0.0625f);
      q[2] = (__bf16)(f0.z * 0.0625f); q[3] = (__bf16)(f0.w * 0.0625f);
      q[4] = (__bf16)(f1.x * 0.0625f); q[5] = (__bf16)(f1.y * 0.0625f);
      q[6] = (__bf16)(f1.z * 0.0625f); q[7] = (__bf16)(f1.w * 0.0625f);
      qf[dc] = q;
    }
  }

  f32x4 acc[16];
  const f32x4 fz = {0.f, 0.f, 0.f, 0.f};
  #pragma unroll
  for (int i = 0; i < 16; ++i) acc[i] = fz;
  float m_run = -1e30f;
  float l_run = 0.f;

  const char* vpA = VtB + h * 128 + ((32 * g)      ^ ((h & 7) << 4));
  const char* vpB = VtB + h * 128 + ((32 * g + 16) ^ ((h & 7) << 4));

  if constexpr (USE_WS) {
    const u16* KimgB = (const u16*)Kp + (size_t)b * 64 * 16384;
    const u16* VimgB = (const u16*)Vp + (size_t)b * 64 * 16384;

    // ---- prologue: group A stages tile 0 ----
    if (gid == 0) stage_img(KimgB, VimgB, 0, KsB, VtB, w, lane);
    __syncthreads();

    // ---- alternating main loop: 1 barrier per half-step ----
    for (int s = 0; s < NSUP; ++s) {
      // half-step 2s: A computes tile 2s, B stages tile 2s+1
      if (gid == 0) compute_tile(KsB, vpA, vpB, qf, acc, m_run, l_run, g, h);
      else          stage_img(KimgB, VimgB, 2 * s + 1, KsB, VtB, w, lane);
      __syncthreads();
      // half-step 2s+1: B computes tile 2s+1, A stages tile 2s+2
      if (gid == 0) { if (s < NSUP - 1) stage_img(KimgB, VimgB, 2 * s + 2, KsB, VtB, w, lane); }
      else          compute_tile(KsB, vpA, vpB, qf, acc, m_run, l_run, g, h);
      __syncthreads();
    }

  } else {
    // fallback (fp32 inputs, serial staging) — used only if d_ws is too small
    const float* Kf = (const float*)Kp + (size_t)b * S_LEN * D_DIM;
    const float* Vf = (const float*)Vp + (size_t)b * S_LEN * D_DIM;
    for (int s = 0; s < NSUP; ++s) {
      const int kt = 2 * s + gid;
      __syncthreads();
      #pragma unroll
      for (int i = 0; i < 16; ++i) {
        int flat = i * 256 + ltid;
        int kk = flat >> 6;
        int d  = (flat & 63) * 4;
        float4 fk = *reinterpret_cast<const float4*>(Kf + (size_t)(kt * 64 + kk) * D_DIM + d);
        *reinterpret_cast<s16x4*>(KsB + kk * 512 + ((d * 2) ^ ((kk & 7) << 4))) = cvt4(fk.x, fk.y, fk.z, fk.w);
      }
      {
        s16x8 lo[4], hi[4];
        #pragma unroll
        for (int r = 0; r < 4; ++r) {
          const float* src = Vf + (size_t)(kt * 64 + kb * 4 + r) * D_DIM + dcq * 16;
          float4 f0 = *reinterpret_cast<const float4*>(src);
          float4 f1 = *reinterpret_cast<const float4*>(src + 4);
          float4 f2 = *reinterpret_cast<const float4*>(src + 8);
          float4 f3 = *reinterpret_cast<const float4*>(src + 12);
          lo[r] = __builtin_shufflevector(cvt4(f0.x, f0.y, f0.z, f0.w),
                                          cvt4(f1.x, f1.y, f1.z, f1.w), 0, 1, 2, 3, 4, 5, 6, 7);
          hi[r] = __builtin_shufflevector(cvt4(f2.x, f2.y, f2.z, f2.w),
                                          cvt4(f3.x, f3.y, f3.z, f3.w), 0, 1, 2, 3, 4, 5, 6, 7);
        }
        #pragma unroll
        for (int j = 0; j < 8; ++j) {
          s16x4 c0, c1;
          c0[0] = lo[0][j]; c0[1] = lo[1][j]; c0[2] = lo[2][j]; c0[3] = lo[3][j];
          c1[0] = hi[0][j]; c1[1] = hi[1][j]; c1[2] = hi[2][j]; c1[3] = hi[3][j];
          const int d0 = dcq * 16 + j;
          const int d1 = d0 + 8;
          *reinterpret_cast<s16x4*>(VtB + d0 * 128 + (Xw ^ ((d0 & 7) << 4))) = c0;
          *reinterpret_cast<s16x4*>(VtB + d1 * 128 + (Xw ^ ((d1 & 7) << 4))) = c1;
        }
      }
      __syncthreads();
      compute_tile(KsB, vpA, vpB, qf, acc, m_run, l_run, g, h);
    }
  }

  // ---- merge group B's state into group A, then epilogue (R9 verbatim) ----
  __syncthreads();   // all compute done; tile buffers are now dead
  float2* mlM = reinterpret_cast<float2*>(smem + 65536);
  if (gid == 1) {
    const int bw = wave - 4;
    char* base = smem + bw * 16384 + lane * 256;
    #pragma unroll
    for (int dt = 0; dt < 16; ++dt) {
      float4 v; v.x = acc[dt][0]; v.y = acc[dt][1]; v.z = acc[dt][2]; v.w = acc[dt][3];
      *reinterpret_cast<float4*>(base + (dt * 16 ^ ((lane & 7) << 4))) = v;
    }
    if (g == 0) { float2 ml; ml.x = m_run; ml.y = l_run; mlM[bw * 16 + h] = ml; }
  }
  __syncthreads();
  if (gid == 0) {
    const float2 ml = mlM[wave * 16 + h];
    const float mB = ml.x, lB = ml.y;
    const float m  = fmaxf(m_run, mB);
    const float sA = __expf(m_run - m);
    const float sB = __expf(mB - m);
    const float l  = l_run * sA + lB * sB;
    float aA[4], aB[4], inv[4];
    #pragma unroll
    for (int r = 0; r < 4; ++r) {
      aA[r]  = __shfl(sA, g * 4 + r);
      aB[r]  = __shfl(sB, g * 4 + r);
      inv[r] = 1.f / __shfl(l, g * 4 + r);
    }
    const char* base = smem + wave * 16384 + lane * 256;
    float* orow0 = Og + ((size_t)b * S_LEN + qbase) * D_DIM;
    #pragma unroll
    for (int dt = 0; dt < 16; ++dt) {
      float4 ab = *reinterpret_cast<const float4*>(base + (dt * 16 ^ ((lane & 7) << 4)));
      orow0[(size_t)(g * 4 + 0) * D_DIM + h + dt * 16] = (acc[dt][0] * aA[0] + ab.x * aB[0]) * inv[0];
      orow0[(size_t)(g * 4 + 1) * D_DIM + h + dt * 16] = (acc[dt][1] * aA[1] + ab.y * aB[1]) * inv[1];
      orow0[(size_t)(g * 4 + 2) * D_DIM + h + dt * 16] = (acc[dt][2] * aA[2] + ab.z * aB[2]) * inv[2];
      orow0[(size_t)(g * 4 + 3) * D_DIM + h + dt * 16] = (acc[dt][3] * aA[3] + ab.w * aB[3]) * inv[3];
    }
  }
}

extern "C" void kernel_launch(void* const* d_in, const int* in_sizes, int n_in,
                              void* d_out, int out_size, void* d_ws, size_t ws_size,
                              hipStream_t stream)
{
  const float* Q = (const float*)d_in[0];
  const float* K = (const float*)d_in[1];
  const float* V = (const float*)d_in[2];
  float* O = (float*)d_out;

  const size_t nelem = (size_t)NBATCH * S_LEN * D_DIM;   // 4,194,304
  const size_t need  = 2 * nelem * sizeof(u16);          // 16 MiB

  if (ws_size >= need) {
    u16* Kimg = (u16*)d_ws;
    u16* Vimg = Kimg + nelem;
    build_kimg<<<256, 256, 0, stream>>>(K, Kimg);
    build_vimg<<<256, 256, 0, stream>>>(V, Vimg);
    attn_fwd_kernel<true><<<256, 512, 0, stream>>>(Q, (const void*)Kimg, (const void*)Vimg, O);
  } else {
    attn_fwd_kernel<false><<<256, 512, 0, stream>>>(Q, (const void*)K, (const void*)V, O);
  }
}